// Round 3
// baseline (2713.093 us; speedup 1.0000x reference)
//
#include <hip/hip_runtime.h>
#include <hip/hip_fp16.h>
#include <math.h>

// Problem constants (match reference)
constexpr int kP  = 3;
constexpr int kN  = 50000;
constexpr int kE  = 256000;
constexpr int kC  = 5;
constexpr int kF  = 68;    // F_IN + F_NODE
constexpr int kF2 = 136;   // 2*F
constexpr int kFE = 16;    // F_EDGE
constexpr int kFN = 64;    // F_NODE
constexpr int kOfsStride = 50004;  // (N+1) rounded up to mult of 4 ints
constexpr int kNChunks = (kN + 1023) / 1024;  // 49
constexpr int kPartStride = 64;

__device__ __forceinline__ float fast_tanh(float x) {
  float t = fminf(fmaxf(x, -15.f), 15.f);
  float e = __expf(2.f * t);
  return (e - 1.f) / (e + 1.f);
}

// ---------------------------------------------------------------------------
// 1) Histogram of in-degrees (all planes): counts[p][dst]++
// ---------------------------------------------------------------------------
__global__ __launch_bounds__(256) void hist_kernel(
    const int* __restrict__ ei,   // [P, 2, E]
    int* __restrict__ counts)     // [P, N]
{
  int p = blockIdx.y;
  int e = blockIdx.x * 256 + threadIdx.x;
  if (e >= kE) return;
  int dst = ei[(size_t)p * 2 * kE + kE + e];
  atomicAdd(&counts[p * kN + dst], 1);
}

// ---------------------------------------------------------------------------
// 2) Three-phase parallel exclusive scan.
// ---------------------------------------------------------------------------
__global__ __launch_bounds__(256) void scanA_kernel(
    const int* __restrict__ counts,   // [P, N]
    int* __restrict__ offsets,        // [P, kOfsStride]
    int* __restrict__ partials)       // [P, kPartStride]
{
  int p = blockIdx.y, chunk = blockIdx.x, tid = threadIdx.x;
  const int* cnt = counts + p * kN;
  int base = chunk * 1024 + tid * 4;
  int v0 = 0, v1 = 0, v2 = 0, v3 = 0;
  if (base + 3 < kN) {
    int4 v = *reinterpret_cast<const int4*>(cnt + base);
    v0 = v.x; v1 = v.y; v2 = v.z; v3 = v.w;
  } else if (base < kN) {
    v0 = cnt[base];
    if (base + 1 < kN) v1 = cnt[base + 1];
    if (base + 2 < kN) v2 = cnt[base + 2];
  }
  int s0 = v0, s1 = s0 + v1, s2 = s1 + v2, s3 = s2 + v3;
  __shared__ int buf[256];
  buf[tid] = s3;
  __syncthreads();
  for (int d = 1; d < 256; d <<= 1) {
    int t = (tid >= d) ? buf[tid - d] : 0;
    __syncthreads();
    buf[tid] += t;
    __syncthreads();
  }
  int excl = buf[tid] - s3;  // exclusive base of this thread within chunk
  int* ofs = offsets + p * kOfsStride;
  if (base + 3 < kN) {
    *reinterpret_cast<int4*>(ofs + base) =
        make_int4(excl, excl + s0, excl + s1, excl + s2);
  } else if (base < kN) {
    ofs[base] = excl;
    if (base + 1 < kN) ofs[base + 1] = excl + s0;
    if (base + 2 < kN) ofs[base + 2] = excl + s1;
  }
  if (tid == 255) partials[p * kPartStride + chunk] = buf[255];
}

__global__ __launch_bounds__(64) void scanB_kernel(int* __restrict__ partials)
{
  int p = blockIdx.x, tid = threadIdx.x;
  int v = (tid < kNChunks) ? partials[p * kPartStride + tid] : 0;
  __shared__ int buf[64];
  buf[tid] = v;
  __syncthreads();
  for (int d = 1; d < 64; d <<= 1) {
    int t = (tid >= d) ? buf[tid - d] : 0;
    __syncthreads();
    buf[tid] += t;
    __syncthreads();
  }
  partials[p * kPartStride + tid] = buf[tid] - v;  // exclusive
  // slot kNChunks now holds the grand total (its input was 0)
}

__global__ __launch_bounds__(256) void scanC_kernel(
    int* __restrict__ offsets,        // [P, kOfsStride]
    const int* __restrict__ partials, // [P, kPartStride]
    int* __restrict__ cursor)         // [P, N]
{
  int p = blockIdx.y, chunk = blockIdx.x, tid = threadIdx.x;
  int add = partials[p * kPartStride + chunk];
  int base = chunk * 1024 + tid * 4;
  int* ofs = offsets + p * kOfsStride;
  int* cur = cursor + p * kN;
  if (base + 3 < kN) {
    int4 v = *reinterpret_cast<const int4*>(ofs + base);
    v.x += add; v.y += add; v.z += add; v.w += add;
    *reinterpret_cast<int4*>(ofs + base) = v;
    *reinterpret_cast<int4*>(cur + base) = v;
  } else if (base < kN) {
#pragma unroll
    for (int k = 0; k < 3; ++k) {
      if (base + k < kN) {
        int o = ofs[base + k] + add;
        ofs[base + k] = o;
        cur[base + k] = o;
      }
    }
  }
  if (chunk == 0 && tid == 0) ofs[kN] = partials[p * kPartStride + kNChunks];
}

// ---------------------------------------------------------------------------
// 3) Per-node edge-layer-1 precompute:
//    yi[n,c,g] = We1[c][g][0:68]   . x[n,c,:]
//    yj[n,c,g] = We1[c][g][68:136] . x[n,c,:]
// ---------------------------------------------------------------------------
__global__ __launch_bounds__(256) void pre_kernel(
    const float* __restrict__ x,    // [N, C, F] (this plane)
    const float* __restrict__ We1,  // [C, 16, 136]
    float* __restrict__ yi,         // [N, C, 16]
    float* __restrict__ yj)         // [N, C, 16]
{
  int n = blockIdx.x * 256 + threadIdx.x;
  int c = blockIdx.y;
  if (n >= kN) return;

  const float4* xr = reinterpret_cast<const float4*>(x + ((size_t)n * kC + c) * kF);
  const float* Wc = We1 + c * (kFE * kF2);

  float ai[kFE], aj[kFE];
#pragma unroll
  for (int g = 0; g < kFE; ++g) { ai[g] = 0.f; aj[g] = 0.f; }

  for (int q = 0; q < kF / 4; ++q) {  // 17
    float4 v = xr[q];
#pragma unroll
    for (int g = 0; g < kFE; ++g) {
      const float* wi = Wc + g * kF2 + 4 * q;
      const float* wj = wi + kF;
      float a = ai[g];
      a = fmaf(wi[0], v.x, a); a = fmaf(wi[1], v.y, a);
      a = fmaf(wi[2], v.z, a); a = fmaf(wi[3], v.w, a);
      ai[g] = a;
      float b = aj[g];
      b = fmaf(wj[0], v.x, b); b = fmaf(wj[1], v.y, b);
      b = fmaf(wj[2], v.z, b); b = fmaf(wj[3], v.w, b);
      aj[g] = b;
    }
  }

  float4* oi = reinterpret_cast<float4*>(yi + ((size_t)n * kC + c) * kFE);
  float4* oj = reinterpret_cast<float4*>(yj + ((size_t)n * kC + c) * kFE);
#pragma unroll
  for (int k = 0; k < 4; ++k) {
    oi[k] = make_float4(ai[4*k], ai[4*k+1], ai[4*k+2], ai[4*k+3]);
    oj[k] = make_float4(aj[4*k], aj[4*k+1], aj[4*k+2], aj[4*k+3]);
  }
}

// ---------------------------------------------------------------------------
// 3b) Per-node aggr-half precompute of node layer 1:
//     z[n,c,g] = Wn1[c][g][68:136] . x[n,c,:]    (stored fp16)
// ---------------------------------------------------------------------------
__global__ __launch_bounds__(256) void pre_z_kernel(
    const float* __restrict__ x,    // [N, C, F] (this plane)
    const float* __restrict__ Wn1,  // [C, 64, 136]
    __half* __restrict__ z)         // [N, C, 64]
{
  int n = blockIdx.x * 256 + threadIdx.x;
  int c = blockIdx.y;
  if (n >= kN) return;

  float4 xr[kF / 4];
  const float4* xp = reinterpret_cast<const float4*>(x + ((size_t)n * kC + c) * kF);
#pragma unroll
  for (int q = 0; q < kF / 4; ++q) xr[q] = xp[q];

  const float* W = Wn1 + c * (kFN * kF2) + kF;  // aggr-half columns
  uint4* zp = reinterpret_cast<uint4*>(z + ((size_t)n * kC + c) * kFN);

  for (int g0 = 0; g0 < kFN; g0 += 8) {
    float acc[8];
#pragma unroll
    for (int t = 0; t < 8; ++t) acc[t] = 0.f;
#pragma unroll
    for (int q = 0; q < kF / 4; ++q) {
      float4 v = xr[q];
#pragma unroll
      for (int t = 0; t < 8; ++t) {
        const float* wr = W + (size_t)(g0 + t) * kF2 + 4 * q;
        float a = acc[t];
        a = fmaf(wr[0], v.x, a); a = fmaf(wr[1], v.y, a);
        a = fmaf(wr[2], v.z, a); a = fmaf(wr[3], v.w, a);
        acc[t] = a;
      }
    }
    __half2 p0 = __floats2half2_rn(acc[0], acc[1]);
    __half2 p1 = __floats2half2_rn(acc[2], acc[3]);
    __half2 p2 = __floats2half2_rn(acc[4], acc[5]);
    __half2 p3 = __floats2half2_rn(acc[6], acc[7]);
    uint4 pk;
    pk.x = *reinterpret_cast<unsigned int*>(&p0);
    pk.y = *reinterpret_cast<unsigned int*>(&p1);
    pk.z = *reinterpret_cast<unsigned int*>(&p2);
    pk.w = *reinterpret_cast<unsigned int*>(&p3);
    zp[g0 >> 3] = pk;
  }
}

// ---------------------------------------------------------------------------
// 4) Edge kernel: softmax weights from precomputed yi/yj, scattered into the
//    CSR slot claimed via cursor (int atomic).
// ---------------------------------------------------------------------------
__global__ __launch_bounds__(256) void edge_kernel(
    const int*   __restrict__ ei,         // [2, E] (this plane)
    const float* __restrict__ yi,         // [N, C, 16]
    const float* __restrict__ yj,         // [N, C, 16]
    const float* __restrict__ be1,        // [C, 16]
    const float* __restrict__ We2,        // [C, 16]
    const float* __restrict__ be2,        // [C]
    int*         __restrict__ cursor,     // [N] (this plane)
    int*         __restrict__ sorted_src, // [E]
    float*       __restrict__ w_sorted)   // [E, C]
{
  int e = blockIdx.x * 256 + threadIdx.x;
  if (e >= kE) return;
  int src = ei[e];
  int dst = ei[kE + e];

  const float* yid = yi + (size_t)dst * (kC * kFE);
  const float* yjs = yj + (size_t)src * (kC * kFE);

  float logits[kC];
#pragma unroll
  for (int c = 0; c < kC; ++c) {
    const float4* a = reinterpret_cast<const float4*>(yid + c * kFE);
    const float4* b = reinterpret_cast<const float4*>(yjs + c * kFE);
    float lg = be2[c];
#pragma unroll
    for (int qq = 0; qq < 4; ++qq) {
      float4 av = a[qq];
      float4 bv = b[qq];
      const float* bb = be1 + c * kFE + 4 * qq;
      const float* w2 = We2 + c * kFE + 4 * qq;
      lg = fmaf(w2[0], fast_tanh(av.x + bv.x + bb[0]), lg);
      lg = fmaf(w2[1], fast_tanh(av.y + bv.y + bb[1]), lg);
      lg = fmaf(w2[2], fast_tanh(av.z + bv.z + bb[2]), lg);
      lg = fmaf(w2[3], fast_tanh(av.w + bv.w + bb[3]), lg);
    }
    logits[c] = lg;
  }

  float m = logits[0];
#pragma unroll
  for (int c = 1; c < kC; ++c) m = fmaxf(m, logits[c]);
  float wgt[kC];
  float s = 0.f;
#pragma unroll
  for (int c = 0; c < kC; ++c) { wgt[c] = __expf(logits[c] - m); s += wgt[c]; }
  float inv = 1.f / s;

  int pos = atomicAdd(&cursor[dst], 1);
  sorted_src[pos] = src;
#pragma unroll
  for (int c = 0; c < kC; ++c) w_sorted[(size_t)pos * kC + c] = wgt[c] * inv;
}

// ---------------------------------------------------------------------------
// 5) Node kernel, pair-split: 2 threads per (n,c), each owns 32 of the 64
//    h-components. h crosses the pair via a fp16 LDS tile (144-B rows).
//    Layer-2 LDS read: 2x uint4 per q step = 16 halves (bug fixed: one
//    uint4 holds only 8 halves).
// ---------------------------------------------------------------------------
__global__ __launch_bounds__(256) void node_pair_kernel(
    const float*  __restrict__ x,          // [N, C, F] (this plane)
    const int*    __restrict__ offsets,    // [N+1] (this plane)
    const int*    __restrict__ sorted_src, // [E]
    const float*  __restrict__ w_sorted,   // [E, C]
    const __half* __restrict__ z,          // [N, C, 64]
    const float*  __restrict__ Wn1,        // [C, 64, 136]
    const float*  __restrict__ bn1,        // [C, 64]
    const float*  __restrict__ Wn2,        // [C, 64, 64]
    const float*  __restrict__ bn2,        // [C, 64]
    float*        __restrict__ out)        // [N, C, 64] (this plane)
{
  __shared__ __align__(16) unsigned char hsm[128 * 144];
  int tid = threadIdx.x;
  int i = blockIdx.x * 256 + tid;
  int n = i >> 1;
  int half = i & 1;
  int c = blockIdx.y;
  bool active = (n < kN);
  int pr = tid >> 1;

  if (active) {
    int beg = offsets[n];
    int end = offsets[n + 1];

    float h[32];
#pragma unroll
    for (int g = 0; g < 32; ++g) h[g] = 0.f;

    // Gather own 64-B half of each z row.
    for (int s = beg; s < end; ++s) {
      int sj = sorted_src[s];
      float w = w_sorted[(size_t)s * kC + c];
      const uint4* zp = reinterpret_cast<const uint4*>(
          z + ((size_t)sj * kC + c) * kFN + half * 32);
#pragma unroll
      for (int u = 0; u < 4; ++u) {
        uint4 v = zp[u];
        float2 f0 = __half22float2(*reinterpret_cast<const __half2*>(&v.x));
        float2 f1 = __half22float2(*reinterpret_cast<const __half2*>(&v.y));
        float2 f2 = __half22float2(*reinterpret_cast<const __half2*>(&v.z));
        float2 f3 = __half22float2(*reinterpret_cast<const __half2*>(&v.w));
        h[8*u+0] = fmaf(w, f0.x, h[8*u+0]);
        h[8*u+1] = fmaf(w, f0.y, h[8*u+1]);
        h[8*u+2] = fmaf(w, f1.x, h[8*u+2]);
        h[8*u+3] = fmaf(w, f1.y, h[8*u+3]);
        h[8*u+4] = fmaf(w, f2.x, h[8*u+4]);
        h[8*u+5] = fmaf(w, f2.y, h[8*u+5]);
        h[8*u+6] = fmaf(w, f3.x, h[8*u+6]);
        h[8*u+7] = fmaf(w, f3.y, h[8*u+7]);
      }
    }

    // x-half of node layer 1 for our 32 output rows.
    const float* W1 = Wn1 + c * (kFN * kF2) + (size_t)(half * 32) * kF2;
    const float4* xp = reinterpret_cast<const float4*>(x + ((size_t)n * kC + c) * kF);
    for (int q = 0; q < kF / 4; ++q) {  // 17
      float4 v = xp[q];
#pragma unroll
      for (int j = 0; j < 32; ++j) {
        const float* wr = W1 + (size_t)j * kF2 + 4 * q;
        float a = h[j];
        a = fmaf(wr[0], v.x, a);
        a = fmaf(wr[1], v.y, a);
        a = fmaf(wr[2], v.z, a);
        a = fmaf(wr[3], v.w, a);
        h[j] = a;
      }
    }

    const float* b1 = bn1 + c * kFN + half * 32;
#pragma unroll
    for (int j = 0; j < 32; ++j) h[j] = fast_tanh(h[j] + b1[j]);

    // Pack to fp16 and publish our half into the pair's LDS row.
    uint4* wp = reinterpret_cast<uint4*>(hsm + pr * 144 + half * 64);
#pragma unroll
    for (int u = 0; u < 4; ++u) {
      __half2 a = __floats2half2_rn(h[8*u+0], h[8*u+1]);
      __half2 b = __floats2half2_rn(h[8*u+2], h[8*u+3]);
      __half2 d = __floats2half2_rn(h[8*u+4], h[8*u+5]);
      __half2 e = __floats2half2_rn(h[8*u+6], h[8*u+7]);
      uint4 pk;
      pk.x = *reinterpret_cast<unsigned int*>(&a);
      pk.y = *reinterpret_cast<unsigned int*>(&b);
      pk.z = *reinterpret_cast<unsigned int*>(&d);
      pk.w = *reinterpret_cast<unsigned int*>(&e);
      wp[u] = pk;
    }
  }

  __syncthreads();
  if (!active) return;

  // Layer 2: full 64-wide h from LDS, our 32 output rows, 16 at a time.
  const float* W2 = Wn2 + c * (kFN * kFN) + (size_t)(half * 32) * kFN;
  const float* b2 = bn2 + c * kFN + half * 32;
  float* op = out + ((size_t)n * kC + c) * kFN + half * 32;
  const uint4* hp = reinterpret_cast<const uint4*>(hsm + pr * 144);

  for (int jb = 0; jb < 32; jb += 16) {
    float acc[16];
#pragma unroll
    for (int j = 0; j < 16; ++j) acc[j] = b2[jb + j];
#pragma unroll
    for (int q = 0; q < 4; ++q) {  // 16 h-values per step (2 x uint4)
      uint4 hv0 = hp[2 * q];
      uint4 hv1 = hp[2 * q + 1];
      float f[16];
      const __half2* h0 = reinterpret_cast<const __half2*>(&hv0);
      const __half2* h1 = reinterpret_cast<const __half2*>(&hv1);
#pragma unroll
      for (int t = 0; t < 4; ++t) {
        float2 ff = __half22float2(h0[t]);
        f[2*t]   = ff.x;
        f[2*t+1] = ff.y;
        float2 gg = __half22float2(h1[t]);
        f[8+2*t]   = gg.x;
        f[8+2*t+1] = gg.y;
      }
#pragma unroll
      for (int j = 0; j < 16; ++j) {
        const float* wr = W2 + (size_t)(jb + j) * kFN + q * 16;
        float a = acc[j];
        a = fmaf(wr[0],  f[0],  a);  a = fmaf(wr[1],  f[1],  a);
        a = fmaf(wr[2],  f[2],  a);  a = fmaf(wr[3],  f[3],  a);
        a = fmaf(wr[4],  f[4],  a);  a = fmaf(wr[5],  f[5],  a);
        a = fmaf(wr[6],  f[6],  a);  a = fmaf(wr[7],  f[7],  a);
        a = fmaf(wr[8],  f[8],  a);  a = fmaf(wr[9],  f[9],  a);
        a = fmaf(wr[10], f[10], a);  a = fmaf(wr[11], f[11], a);
        a = fmaf(wr[12], f[12], a);  a = fmaf(wr[13], f[13], a);
        a = fmaf(wr[14], f[14], a);  a = fmaf(wr[15], f[15], a);
        acc[j] = a;
      }
    }
    float4* o4 = reinterpret_cast<float4*>(op + jb);
#pragma unroll
    for (int u = 0; u < 4; ++u)
      o4[u] = make_float4(fast_tanh(acc[4*u]),   fast_tanh(acc[4*u+1]),
                          fast_tanh(acc[4*u+2]), fast_tanh(acc[4*u+3]));
  }
}

// ---------------------------------------------------------------------------
extern "C" void kernel_launch(void* const* d_in, const int* in_sizes, int n_in,
                              void* d_out, int out_size, void* d_ws, size_t ws_size,
                              hipStream_t stream) {
  const float* x   = (const float*)d_in[0];   // [P, N, C, F]
  const int*   ei  = (const int*)  d_in[1];   // [P, 2, E] (int32 from harness)
  const float* We1 = (const float*)d_in[2];   // [P, C, 16, 136]
  const float* be1 = (const float*)d_in[3];   // [P, C, 16]
  const float* We2 = (const float*)d_in[4];   // [P, C, 1, 16]
  const float* be2 = (const float*)d_in[5];   // [P, C, 1]
  const float* Wn1 = (const float*)d_in[6];   // [P, C, 64, 136]
  const float* bn1 = (const float*)d_in[7];   // [P, C, 64]
  const float* Wn2 = (const float*)d_in[8];   // [P, C, 64, 64]
  const float* bn2 = (const float*)d_in[9];   // [P, C, 64]
  float* out = (float*)d_out;                 // [P, N, C, 64]

  // Workspace layout (~40 MB; all 16B-aligned). z (fp16, 32 MB) overlays
  // yi+yj (dead after edge_kernel; stream-serialized).
  int* counts  = (int*)d_ws;                       // P*N ints
  int* offsets = counts + kP * kN;                 // P*kOfsStride ints
  int* cursor  = offsets + kP * kOfsStride;        // P*N ints
  int* partials = cursor + kP * kN;                // P*kPartStride ints
  int* sorted_src = partials + kP * kPartStride;   // E ints (per-plane reuse)
  float* w_sorted = (float*)(sorted_src + kE);     // E*C floats (reuse)
  float* yi = w_sorted + (size_t)kE * kC;          // N*C*16 floats (reuse)
  float* yj = yi + (size_t)kN * kC * kFE;          // N*C*16 floats (reuse)
  __half* z = (__half*)yi;                         // N*C*64 halves (overlay)

  const size_t planeX = (size_t)kN * kC * kF;

  hipMemsetAsync(counts, 0, (size_t)kP * kN * sizeof(int), stream);
  hist_kernel<<<dim3(kE / 256, kP), 256, 0, stream>>>(ei, counts);
  scanA_kernel<<<dim3(kNChunks, kP), 256, 0, stream>>>(counts, offsets, partials);
  scanB_kernel<<<kP, 64, 0, stream>>>(partials);
  scanC_kernel<<<dim3(kNChunks, kP), 256, 0, stream>>>(offsets, partials, cursor);

  for (int p = 0; p < kP; ++p) {
    const float* xp = x + p * planeX;

    pre_kernel<<<dim3((kN + 255) / 256, kC), 256, 0, stream>>>(
        xp, We1 + (size_t)p * kC * kFE * kF2, yi, yj);

    edge_kernel<<<kE / 256, 256, 0, stream>>>(
        ei + (size_t)p * 2 * kE, yi, yj,
        be1 + (size_t)p * kC * kFE,
        We2 + (size_t)p * kC * kFE,
        be2 + (size_t)p * kC,
        cursor + p * kN, sorted_src, w_sorted);

    pre_z_kernel<<<dim3((kN + 255) / 256, kC), 256, 0, stream>>>(
        xp, Wn1 + (size_t)p * kC * kFN * kF2, z);

    node_pair_kernel<<<dim3((2 * kN + 255) / 256, kC), 256, 0, stream>>>(
        xp, offsets + p * kOfsStride, sorted_src, w_sorted, z,
        Wn1 + (size_t)p * kC * kFN * kF2,
        bn1 + (size_t)p * kC * kFN,
        Wn2 + (size_t)p * kC * kFN * kFN,
        bn2 + (size_t)p * kC * kFN,
        out + (size_t)p * kN * kC * kFN);
  }
}

// Round 4
// 2120.112 us; speedup vs baseline: 1.2797x; 1.2797x over previous
//
#include <hip/hip_runtime.h>
#include <hip/hip_fp16.h>
#include <math.h>

// Problem constants (match reference)
constexpr int kP  = 3;
constexpr int kN  = 50000;
constexpr int kE  = 256000;
constexpr int kC  = 5;
constexpr int kF  = 68;    // F_IN + F_NODE
constexpr int kF2 = 136;   // 2*F
constexpr int kFE = 16;    // F_EDGE
constexpr int kFN = 64;    // F_NODE
constexpr int kOfsStride = 50004;  // (N+1) rounded up to mult of 4 ints
constexpr int kNChunks = (kN + 1023) / 1024;  // 49
constexpr int kPartStride = 64;

__device__ __forceinline__ float fast_tanh(float x) {
  float t = fminf(fmaxf(x, -15.f), 15.f);
  float e = __expf(2.f * t);
  return (e - 1.f) / (e + 1.f);
}

// ---------------------------------------------------------------------------
// 1) Histogram of in-degrees (all planes): counts[p][dst]++
// ---------------------------------------------------------------------------
__global__ __launch_bounds__(256) void hist_kernel(
    const int* __restrict__ ei,   // [P, 2, E]
    int* __restrict__ counts)     // [P, N]
{
  int p = blockIdx.y;
  int e = blockIdx.x * 256 + threadIdx.x;
  if (e >= kE) return;
  int dst = ei[(size_t)p * 2 * kE + kE + e];
  atomicAdd(&counts[p * kN + dst], 1);
}

// ---------------------------------------------------------------------------
// 2) Three-phase parallel exclusive scan.
// ---------------------------------------------------------------------------
__global__ __launch_bounds__(256) void scanA_kernel(
    const int* __restrict__ counts,   // [P, N]
    int* __restrict__ offsets,        // [P, kOfsStride]
    int* __restrict__ partials)       // [P, kPartStride]
{
  int p = blockIdx.y, chunk = blockIdx.x, tid = threadIdx.x;
  const int* cnt = counts + p * kN;
  int base = chunk * 1024 + tid * 4;
  int v0 = 0, v1 = 0, v2 = 0, v3 = 0;
  if (base + 3 < kN) {
    int4 v = *reinterpret_cast<const int4*>(cnt + base);
    v0 = v.x; v1 = v.y; v2 = v.z; v3 = v.w;
  } else if (base < kN) {
    v0 = cnt[base];
    if (base + 1 < kN) v1 = cnt[base + 1];
    if (base + 2 < kN) v2 = cnt[base + 2];
  }
  int s0 = v0, s1 = s0 + v1, s2 = s1 + v2, s3 = s2 + v3;
  __shared__ int buf[256];
  buf[tid] = s3;
  __syncthreads();
  for (int d = 1; d < 256; d <<= 1) {
    int t = (tid >= d) ? buf[tid - d] : 0;
    __syncthreads();
    buf[tid] += t;
    __syncthreads();
  }
  int excl = buf[tid] - s3;  // exclusive base of this thread within chunk
  int* ofs = offsets + p * kOfsStride;
  if (base + 3 < kN) {
    *reinterpret_cast<int4*>(ofs + base) =
        make_int4(excl, excl + s0, excl + s1, excl + s2);
  } else if (base < kN) {
    ofs[base] = excl;
    if (base + 1 < kN) ofs[base + 1] = excl + s0;
    if (base + 2 < kN) ofs[base + 2] = excl + s1;
  }
  if (tid == 255) partials[p * kPartStride + chunk] = buf[255];
}

__global__ __launch_bounds__(64) void scanB_kernel(int* __restrict__ partials)
{
  int p = blockIdx.x, tid = threadIdx.x;
  int v = (tid < kNChunks) ? partials[p * kPartStride + tid] : 0;
  __shared__ int buf[64];
  buf[tid] = v;
  __syncthreads();
  for (int d = 1; d < 64; d <<= 1) {
    int t = (tid >= d) ? buf[tid - d] : 0;
    __syncthreads();
    buf[tid] += t;
    __syncthreads();
  }
  partials[p * kPartStride + tid] = buf[tid] - v;  // exclusive
  // slot kNChunks now holds the grand total (its input was 0)
}

__global__ __launch_bounds__(256) void scanC_kernel(
    int* __restrict__ offsets,        // [P, kOfsStride]
    const int* __restrict__ partials, // [P, kPartStride]
    int* __restrict__ cursor)         // [P, N]
{
  int p = blockIdx.y, chunk = blockIdx.x, tid = threadIdx.x;
  int add = partials[p * kPartStride + chunk];
  int base = chunk * 1024 + tid * 4;
  int* ofs = offsets + p * kOfsStride;
  int* cur = cursor + p * kN;
  if (base + 3 < kN) {
    int4 v = *reinterpret_cast<const int4*>(ofs + base);
    v.x += add; v.y += add; v.z += add; v.w += add;
    *reinterpret_cast<int4*>(ofs + base) = v;
    *reinterpret_cast<int4*>(cur + base) = v;
  } else if (base < kN) {
#pragma unroll
    for (int k = 0; k < 3; ++k) {
      if (base + k < kN) {
        int o = ofs[base + k] + add;
        ofs[base + k] = o;
        cur[base + k] = o;
      }
    }
  }
  if (chunk == 0 && tid == 0) ofs[kN] = partials[p * kPartStride + kNChunks];
}

// ---------------------------------------------------------------------------
// 3) Per-node edge-layer-1 precompute:
//    yi[n,c,g] = We1[c][g][0:68]   . x[n,c,:]
//    yj[n,c,g] = We1[c][g][68:136] . x[n,c,:]
// ---------------------------------------------------------------------------
__global__ __launch_bounds__(256) void pre_kernel(
    const float* __restrict__ x,    // [N, C, F] (this plane)
    const float* __restrict__ We1,  // [C, 16, 136]
    float* __restrict__ yi,         // [N, C, 16]
    float* __restrict__ yj)         // [N, C, 16]
{
  int n = blockIdx.x * 256 + threadIdx.x;
  int c = blockIdx.y;
  if (n >= kN) return;

  const float4* xr = reinterpret_cast<const float4*>(x + ((size_t)n * kC + c) * kF);
  const float* Wc = We1 + c * (kFE * kF2);

  float ai[kFE], aj[kFE];
#pragma unroll
  for (int g = 0; g < kFE; ++g) { ai[g] = 0.f; aj[g] = 0.f; }

  for (int q = 0; q < kF / 4; ++q) {  // 17
    float4 v = xr[q];
#pragma unroll
    for (int g = 0; g < kFE; ++g) {
      const float* wi = Wc + g * kF2 + 4 * q;
      const float* wj = wi + kF;
      float a = ai[g];
      a = fmaf(wi[0], v.x, a); a = fmaf(wi[1], v.y, a);
      a = fmaf(wi[2], v.z, a); a = fmaf(wi[3], v.w, a);
      ai[g] = a;
      float b = aj[g];
      b = fmaf(wj[0], v.x, b); b = fmaf(wj[1], v.y, b);
      b = fmaf(wj[2], v.z, b); b = fmaf(wj[3], v.w, b);
      aj[g] = b;
    }
  }

  float4* oi = reinterpret_cast<float4*>(yi + ((size_t)n * kC + c) * kFE);
  float4* oj = reinterpret_cast<float4*>(yj + ((size_t)n * kC + c) * kFE);
#pragma unroll
  for (int k = 0; k < 4; ++k) {
    oi[k] = make_float4(ai[4*k], ai[4*k+1], ai[4*k+2], ai[4*k+3]);
    oj[k] = make_float4(aj[4*k], aj[4*k+1], aj[4*k+2], aj[4*k+3]);
  }
}

// ---------------------------------------------------------------------------
// 3b) Per-node aggr-half precompute of node layer 1:
//     z[n,c,g] = Wn1[c][g][68:136] . x[n,c,:]    (stored fp16)
// ---------------------------------------------------------------------------
__global__ __launch_bounds__(256) void pre_z_kernel(
    const float* __restrict__ x,    // [N, C, F] (this plane)
    const float* __restrict__ Wn1,  // [C, 64, 136]
    __half* __restrict__ z)         // [N, C, 64]
{
  int n = blockIdx.x * 256 + threadIdx.x;
  int c = blockIdx.y;
  if (n >= kN) return;

  float4 xr[kF / 4];
  const float4* xp = reinterpret_cast<const float4*>(x + ((size_t)n * kC + c) * kF);
#pragma unroll
  for (int q = 0; q < kF / 4; ++q) xr[q] = xp[q];

  const float* W = Wn1 + c * (kFN * kF2) + kF;  // aggr-half columns
  uint4* zp = reinterpret_cast<uint4*>(z + ((size_t)n * kC + c) * kFN);

  for (int g0 = 0; g0 < kFN; g0 += 8) {
    float acc[8];
#pragma unroll
    for (int t = 0; t < 8; ++t) acc[t] = 0.f;
#pragma unroll
    for (int q = 0; q < kF / 4; ++q) {
      float4 v = xr[q];
#pragma unroll
      for (int t = 0; t < 8; ++t) {
        const float* wr = W + (size_t)(g0 + t) * kF2 + 4 * q;
        float a = acc[t];
        a = fmaf(wr[0], v.x, a); a = fmaf(wr[1], v.y, a);
        a = fmaf(wr[2], v.z, a); a = fmaf(wr[3], v.w, a);
        acc[t] = a;
      }
    }
    __half2 p0 = __floats2half2_rn(acc[0], acc[1]);
    __half2 p1 = __floats2half2_rn(acc[2], acc[3]);
    __half2 p2 = __floats2half2_rn(acc[4], acc[5]);
    __half2 p3 = __floats2half2_rn(acc[6], acc[7]);
    uint4 pk;
    pk.x = *reinterpret_cast<unsigned int*>(&p0);
    pk.y = *reinterpret_cast<unsigned int*>(&p1);
    pk.z = *reinterpret_cast<unsigned int*>(&p2);
    pk.w = *reinterpret_cast<unsigned int*>(&p3);
    zp[g0 >> 3] = pk;
  }
}

// ---------------------------------------------------------------------------
// 4) Edge kernel: softmax weights from precomputed yi/yj, scattered into the
//    CSR slot claimed via cursor (int atomic).
// ---------------------------------------------------------------------------
__global__ __launch_bounds__(256) void edge_kernel(
    const int*   __restrict__ ei,         // [2, E] (this plane)
    const float* __restrict__ yi,         // [N, C, 16]
    const float* __restrict__ yj,         // [N, C, 16]
    const float* __restrict__ be1,        // [C, 16]
    const float* __restrict__ We2,        // [C, 16]
    const float* __restrict__ be2,        // [C]
    int*         __restrict__ cursor,     // [N] (this plane)
    int*         __restrict__ sorted_src, // [E]
    float*       __restrict__ w_sorted)   // [E, C]
{
  int e = blockIdx.x * 256 + threadIdx.x;
  if (e >= kE) return;
  int src = ei[e];
  int dst = ei[kE + e];

  const float* yid = yi + (size_t)dst * (kC * kFE);
  const float* yjs = yj + (size_t)src * (kC * kFE);

  float logits[kC];
#pragma unroll
  for (int c = 0; c < kC; ++c) {
    const float4* a = reinterpret_cast<const float4*>(yid + c * kFE);
    const float4* b = reinterpret_cast<const float4*>(yjs + c * kFE);
    float lg = be2[c];
#pragma unroll
    for (int qq = 0; qq < 4; ++qq) {
      float4 av = a[qq];
      float4 bv = b[qq];
      const float* bb = be1 + c * kFE + 4 * qq;
      const float* w2 = We2 + c * kFE + 4 * qq;
      lg = fmaf(w2[0], fast_tanh(av.x + bv.x + bb[0]), lg);
      lg = fmaf(w2[1], fast_tanh(av.y + bv.y + bb[1]), lg);
      lg = fmaf(w2[2], fast_tanh(av.z + bv.z + bb[2]), lg);
      lg = fmaf(w2[3], fast_tanh(av.w + bv.w + bb[3]), lg);
    }
    logits[c] = lg;
  }

  float m = logits[0];
#pragma unroll
  for (int c = 1; c < kC; ++c) m = fmaxf(m, logits[c]);
  float wgt[kC];
  float s = 0.f;
#pragma unroll
  for (int c = 0; c < kC; ++c) { wgt[c] = __expf(logits[c] - m); s += wgt[c]; }
  float inv = 1.f / s;

  int pos = atomicAdd(&cursor[dst], 1);
  sorted_src[pos] = src;
#pragma unroll
  for (int c = 0; c < kC; ++c) w_sorted[(size_t)pos * kC + c] = wgt[c] * inv;
}

// ---------------------------------------------------------------------------
// 5) Node kernel, wave-pair edge-split: adjacent lanes (2k, 2k+1) share one
//    (n,c); each gathers full h[64] over HALF the CSR edge range, combined
//    with __shfl_xor (intra-wave — no barrier, no LDS, no block tail wait).
//    Layers 1/2 computed redundantly by both lanes (keeps weight loads
//    wave-uniform -> scalar); output row store split by lane parity.
// ---------------------------------------------------------------------------
__global__ __launch_bounds__(256) void node_split_kernel(
    const float*  __restrict__ x,          // [N, C, F] (this plane)
    const int*    __restrict__ offsets,    // [N+1] (this plane)
    const int*    __restrict__ sorted_src, // [E]
    const float*  __restrict__ w_sorted,   // [E, C]
    const __half* __restrict__ z,          // [N, C, 64]
    const float*  __restrict__ Wn1,        // [C, 64, 136]
    const float*  __restrict__ bn1,        // [C, 64]
    const float*  __restrict__ Wn2,        // [C, 64, 64]
    const float*  __restrict__ bn2,        // [C, 64]
    float*        __restrict__ out)        // [N, C, 64] (this plane)
{
  int i = blockIdx.x * 256 + threadIdx.x;
  int n = i >> 1;
  int half = i & 1;        // lane parity; pair lanes (2k,2k+1) share node n
  int c = blockIdx.y;
  if (n >= kN) return;     // whole pairs drop out together -> shfl safe

  int beg = offsets[n];
  int end = offsets[n + 1];
  int deg = end - beg;
  int hcnt = (deg + 1) >> 1;          // ceil(deg/2)
  int s0 = beg + half * hcnt;         // lane 0: [beg, beg+hcnt)
  int s1 = half ? end : beg + hcnt;   // lane 1: [beg+hcnt, end)

  float h[kFN];
#pragma unroll
  for (int g = 0; g < kFN; ++g) h[g] = 0.f;

  // Gather own half of the edge range; full 128-B z row per edge.
  for (int s = s0; s < s1; ++s) {
    int sj = sorted_src[s];
    float w = w_sorted[(size_t)s * kC + c];
    const uint4* zp = reinterpret_cast<const uint4*>(
        z + ((size_t)sj * kC + c) * kFN);
#pragma unroll
    for (int u = 0; u < 8; ++u) {
      uint4 v = zp[u];
      float2 f0 = __half22float2(*reinterpret_cast<const __half2*>(&v.x));
      float2 f1 = __half22float2(*reinterpret_cast<const __half2*>(&v.y));
      float2 f2 = __half22float2(*reinterpret_cast<const __half2*>(&v.z));
      float2 f3 = __half22float2(*reinterpret_cast<const __half2*>(&v.w));
      h[8*u+0] = fmaf(w, f0.x, h[8*u+0]);
      h[8*u+1] = fmaf(w, f0.y, h[8*u+1]);
      h[8*u+2] = fmaf(w, f1.x, h[8*u+2]);
      h[8*u+3] = fmaf(w, f1.y, h[8*u+3]);
      h[8*u+4] = fmaf(w, f2.x, h[8*u+4]);
      h[8*u+5] = fmaf(w, f2.y, h[8*u+5]);
      h[8*u+6] = fmaf(w, f3.x, h[8*u+6]);
      h[8*u+7] = fmaf(w, f3.y, h[8*u+7]);
    }
  }

  // Combine the two half-gathers across the lane pair (no barrier).
#pragma unroll
  for (int g = 0; g < kFN; ++g) h[g] += __shfl_xor(h[g], 1);

  // x-half of node layer 1 (redundant in pair; weights wave-uniform).
  const float* W1 = Wn1 + c * (kFN * kF2);
  const float4* xp = reinterpret_cast<const float4*>(x + ((size_t)n * kC + c) * kF);
  for (int q = 0; q < kF / 4; ++q) {  // 17
    float4 v = xp[q];
#pragma unroll
    for (int g = 0; g < kFN; ++g) {
      const float* wr = W1 + (size_t)g * kF2 + 4 * q;
      float a = h[g];
      a = fmaf(wr[0], v.x, a);
      a = fmaf(wr[1], v.y, a);
      a = fmaf(wr[2], v.z, a);
      a = fmaf(wr[3], v.w, a);
      h[g] = a;
    }
  }

  const float* b1 = bn1 + c * kFN;
#pragma unroll
  for (int g = 0; g < kFN; ++g) h[g] = fast_tanh(h[g] + b1[g]);

  // Layer 2 (redundant compute, parity-split store: lane 0 writes outputs
  // 0..31, lane 1 writes 32..63 -> no duplicate write traffic).
  const float* W2 = Wn2 + c * (kFN * kFN);
  const float* b2 = bn2 + c * kFN;
  float* op = out + ((size_t)n * kC + c) * kFN;
  for (int g2 = 0; g2 < kFN; g2 += 4) {
    float a0 = b2[g2], a1 = b2[g2 + 1], a2 = b2[g2 + 2], a3 = b2[g2 + 3];
    const float* w0 = W2 + (size_t)g2 * kFN;
#pragma unroll
    for (int k = 0; k < kFN; ++k) {
      float hk = h[k];
      a0 = fmaf(w0[k],            hk, a0);
      a1 = fmaf(w0[kFN + k],      hk, a1);
      a2 = fmaf(w0[2 * kFN + k],  hk, a2);
      a3 = fmaf(w0[3 * kFN + k],  hk, a3);
    }
    if ((g2 >> 5) == half) {
      *reinterpret_cast<float4*>(op + g2) =
          make_float4(fast_tanh(a0), fast_tanh(a1),
                      fast_tanh(a2), fast_tanh(a3));
    }
  }
}

// ---------------------------------------------------------------------------
extern "C" void kernel_launch(void* const* d_in, const int* in_sizes, int n_in,
                              void* d_out, int out_size, void* d_ws, size_t ws_size,
                              hipStream_t stream) {
  const float* x   = (const float*)d_in[0];   // [P, N, C, F]
  const int*   ei  = (const int*)  d_in[1];   // [P, 2, E] (int32 from harness)
  const float* We1 = (const float*)d_in[2];   // [P, C, 16, 136]
  const float* be1 = (const float*)d_in[3];   // [P, C, 16]
  const float* We2 = (const float*)d_in[4];   // [P, C, 1, 16]
  const float* be2 = (const float*)d_in[5];   // [P, C, 1]
  const float* Wn1 = (const float*)d_in[6];   // [P, C, 64, 136]
  const float* bn1 = (const float*)d_in[7];   // [P, C, 64]
  const float* Wn2 = (const float*)d_in[8];   // [P, C, 64, 64]
  const float* bn2 = (const float*)d_in[9];   // [P, C, 64]
  float* out = (float*)d_out;                 // [P, N, C, 64]

  // Workspace layout (~40 MB; all 16B-aligned). z (fp16, 32 MB) overlays
  // yi+yj (dead after edge_kernel; stream-serialized).
  int* counts  = (int*)d_ws;                       // P*N ints
  int* offsets = counts + kP * kN;                 // P*kOfsStride ints
  int* cursor  = offsets + kP * kOfsStride;        // P*N ints
  int* partials = cursor + kP * kN;                // P*kPartStride ints
  int* sorted_src = partials + kP * kPartStride;   // E ints (per-plane reuse)
  float* w_sorted = (float*)(sorted_src + kE);     // E*C floats (reuse)
  float* yi = w_sorted + (size_t)kE * kC;          // N*C*16 floats (reuse)
  float* yj = yi + (size_t)kN * kC * kFE;          // N*C*16 floats (reuse)
  __half* z = (__half*)yi;                         // N*C*64 halves (overlay)

  const size_t planeX = (size_t)kN * kC * kF;

  hipMemsetAsync(counts, 0, (size_t)kP * kN * sizeof(int), stream);
  hist_kernel<<<dim3(kE / 256, kP), 256, 0, stream>>>(ei, counts);
  scanA_kernel<<<dim3(kNChunks, kP), 256, 0, stream>>>(counts, offsets, partials);
  scanB_kernel<<<kP, 64, 0, stream>>>(partials);
  scanC_kernel<<<dim3(kNChunks, kP), 256, 0, stream>>>(offsets, partials, cursor);

  for (int p = 0; p < kP; ++p) {
    const float* xp = x + p * planeX;

    pre_kernel<<<dim3((kN + 255) / 256, kC), 256, 0, stream>>>(
        xp, We1 + (size_t)p * kC * kFE * kF2, yi, yj);

    edge_kernel<<<kE / 256, 256, 0, stream>>>(
        ei + (size_t)p * 2 * kE, yi, yj,
        be1 + (size_t)p * kC * kFE,
        We2 + (size_t)p * kC * kFE,
        be2 + (size_t)p * kC,
        cursor + p * kN, sorted_src, w_sorted);

    pre_z_kernel<<<dim3((kN + 255) / 256, kC), 256, 0, stream>>>(
        xp, Wn1 + (size_t)p * kC * kFN * kF2, z);

    node_split_kernel<<<dim3((2 * kN + 255) / 256, kC), 256, 0, stream>>>(
        xp, offsets + p * kOfsStride, sorted_src, w_sorted, z,
        Wn1 + (size_t)p * kC * kFN * kF2,
        bn1 + (size_t)p * kC * kFN,
        Wn2 + (size_t)p * kC * kFN * kFN,
        bn2 + (size_t)p * kC * kFN,
        out + (size_t)p * kN * kC * kFN);
  }
}